// Round 2
// baseline (359.163 us; speedup 1.0000x reference)
//
#include <hip/hip_runtime.h>
#include <hip/hip_bf16.h>

// Problem: B=8192, IN=1024, H=1024, G=2, hg=512, WR=64, UR=[64,64]
// All global tensors are FLOAT32 (per reference). MFMA runs on bf16
// converted in-register; weights are pre-converted into a bf16 workspace.
//
// ws layout (bytes):
//   T    @ 0        : 8192 x 320 bf16  = 5,242,880   (rank-space intermediate)
//   uxT  @ 5242880  : 64 x 1024 bf16   = 131,072     (u_x transposed)
//   uhT  @ 5373952  : 4 x 64 x 512 bf16= 262,144     (u_h segments transposed)
//   Wh   @ 5636096  : 2 x 2048 x 128   = 1,048,576   (v_h concat+transposed)
// total ~6.7 MB

typedef __bf16 bf16_t;
typedef __bf16 bf16x8 __attribute__((ext_vector_type(8)));
typedef float f32x4 __attribute__((ext_vector_type(4)));

#define MFMA16x16x32(a, b, c) __builtin_amdgcn_mfma_f32_16x16x32_bf16((a), (b), (c), 0, 0, 0)

#define T_OFF 0
#define UXT_OFF 5242880
#define UHT_OFF 5373952
#define WH_OFF 5636096

__device__ inline bf16x8 load8_f32_bf16(const float* __restrict__ p) {
  float4 a = *(const float4*)p;
  float4 b = *(const float4*)(p + 4);
  bf16x8 r;
  r[0] = (bf16_t)a.x; r[1] = (bf16_t)a.y; r[2] = (bf16_t)a.z; r[3] = (bf16_t)a.w;
  r[4] = (bf16_t)b.x; r[5] = (bf16_t)b.y; r[6] = (bf16_t)b.z; r[7] = (bf16_t)b.w;
  return r;
}

// ---------------- prep: weight transposes + f32->bf16 ----------------
// uxT[j][k]   = u_x[k][j]                        (64 x 1024)
// uhT[s][j][d]: s0=(uh0,g0) s1=(uh1,g0) s2=(uh0,g1) s3=(uh1,g1)   (4 x 64 x 512)
// Wh[g][kp][r] = r<64 ? v_h_0[g][r][kp] : v_h_1[g][r-64][kp]      (2 x 2048 x 128)
__global__ __launch_bounds__(256) void prep_kernel(
    const float* __restrict__ u_x, const float* __restrict__ u_h_0,
    const float* __restrict__ u_h_1, const float* __restrict__ v_h_0,
    const float* __restrict__ v_h_1, bf16_t* __restrict__ uxT,
    bf16_t* __restrict__ uhT, bf16_t* __restrict__ Wh) {
  int i = blockIdx.x * 256 + threadIdx.x;
  if (i < 65536) {
    int j = i >> 10, k = i & 1023;
    uxT[i] = (bf16_t)u_x[k * 64 + j];
  } else if (i < 65536 + 131072) {
    int i2 = i - 65536;
    int s = i2 >> 15, rem = i2 & 32767;
    int j = rem >> 9, d = rem & 511;
    const float* src = (s & 1) ? u_h_1 : u_h_0;
    int goff = (s >> 1) ? 32768 : 0;  // g stride = 512*64
    uhT[i2] = (bf16_t)src[goff + d * 64 + j];
  } else if (i < 65536 + 131072 + 524288) {
    int i3 = i - 196608;
    int g = i3 >> 18, rem = i3 & 262143;
    int kp = rem >> 7, r = rem & 127;
    const float* src = (r < 64) ? v_h_0 : v_h_1;
    Wh[i3] = (bf16_t)src[g * 131072 + (r & 63) * 2048 + kp];  // g stride = 64*2048
  }
}

// ---------------- phase1: T = [x@u_x | h-slices @ u_h segs] ----------------
// 20 n-tiles of 16 cols; wave w handles tiles w, w+4, ..., w+16.
__global__ __launch_bounds__(256) void phase1_kernel(
    const float* __restrict__ x, const float* __restrict__ h,
    const bf16_t* __restrict__ uxT, const bf16_t* __restrict__ uhT,
    bf16_t* __restrict__ T) {
  const int b0 = blockIdx.x * 16;
  const int wv = threadIdx.x >> 6;
  const int lane = threadIdx.x & 63;
  const int lo = lane & 15, quad = lane >> 4;
  const int hoff[4] = {0, 512, 512, 0};

  for (int idx = 0; idx < 5; ++idx) {
    int t = wv + 4 * idx;  // 0..19
    const float* aBase;
    const bf16_t* wBase;
    int K;
    if (t < 4) {
      aBase = x + (size_t)(b0 + lo) * 1024;
      wBase = uxT + (size_t)(16 * t + lo) * 1024;
      K = 1024;
    } else {
      int s = (t - 4) >> 2, sub = (t - 4) & 3;
      aBase = h + (size_t)(b0 + lo) * 1024 + hoff[s];
      wBase = uhT + (size_t)(s * 64 + 16 * sub + lo) * 512;
      K = 512;
    }
    f32x4 acc = {0.f, 0.f, 0.f, 0.f};
    for (int k = 0; k < K; k += 32) {
      bf16x8 af = load8_f32_bf16(aBase + k + quad * 8);
      bf16x8 bf = *(const bf16x8*)(wBase + k + quad * 8);
      acc = MFMA16x16x32(af, bf, acc);
    }
    // D: col = lane&15 -> n, row = quad*4 + r -> b
#pragma unroll
    for (int r = 0; r < 4; ++r) {
      int b = b0 + quad * 4 + r;
      T[(size_t)b * 320 + 16 * t + lo] = (bf16_t)acc[r];
    }
  }
}

// ---------------- phase2: gates + cell update ----------------
// Block tile: 16 b-rows x 64 m-channels (within one group g). Wave w = gate w
// (order f,i,n,o). acc = T[:,0:64] @ v_x_rows^T + T[:,64+g*128:+128] @ Wh_rows^T.
__global__ __launch_bounds__(256) void phase2_kernel(
    const bf16_t* __restrict__ T, const float* __restrict__ v_x,
    const bf16_t* __restrict__ Wh, const float* __restrict__ bias_x,
    const float* __restrict__ bias_h, const float* __restrict__ c,
    float* __restrict__ out) {
  __shared__ float pre[4][16][65];  // +1 pad to break write conflicts

  const int b0 = blockIdx.x * 16;   // 512 b-tiles
  const int m0 = blockIdx.y * 64;   // 16 m-tiles
  const int g = m0 >> 9;            // group
  const int q0 = m0 & 511;          // offset within group
  const int w = threadIdx.x >> 6;   // gate id: 0=f 1=i 2=n 3=o
  const int lane = threadIdx.x & 63;
  const int lo = lane & 15, quad = lane >> 4;

  f32x4 acc[4];
#pragma unroll
  for (int nt = 0; nt < 4; ++nt) acc[nt] = (f32x4){0.f, 0.f, 0.f, 0.f};

  const bf16_t* aBase = T + (size_t)(b0 + lo) * 320;

  // A fragments (shared across nt): GEMM1 k=0..63, GEMM2 k=0..127
  bf16x8 a1[2], a2[4];
#pragma unroll
  for (int kk = 0; kk < 2; ++kk)
    a1[kk] = *(const bf16x8*)(aBase + kk * 32 + quad * 8);
  const bf16_t* aBase2 = aBase + 64 + g * 128;
#pragma unroll
  for (int kk = 0; kk < 4; ++kk)
    a2[kk] = *(const bf16x8*)(aBase2 + kk * 32 + quad * 8);

  // GEMM1: K=64 against v_x rows (row j = gate channel, contiguous 64 f32)
#pragma unroll
  for (int nt = 0; nt < 4; ++nt) {
    const float* wRow = v_x + (size_t)(w * 1024 + m0 + nt * 16 + lo) * 64;
#pragma unroll
    for (int kk = 0; kk < 2; ++kk) {
      bf16x8 bf = load8_f32_bf16(wRow + kk * 32 + quad * 8);
      acc[nt] = MFMA16x16x32(a1[kk], bf, acc[nt]);
    }
  }

  // GEMM2: K=128 against Wh[g] rows (row kp = w*512 + q, contiguous 128 bf16)
  const bf16_t* whg = Wh + (size_t)g * 2048 * 128;
#pragma unroll
  for (int nt = 0; nt < 4; ++nt) {
    const bf16_t* wRow = whg + (size_t)(w * 512 + q0 + nt * 16 + lo) * 128;
#pragma unroll
    for (int kk = 0; kk < 4; ++kk) {
      bf16x8 bf = *(const bf16x8*)(wRow + kk * 32 + quad * 8);
      acc[nt] = MFMA16x16x32(a2[kk], bf, acc[nt]);
    }
  }

  // biases + LDS
#pragma unroll
  for (int nt = 0; nt < 4; ++nt) {
    int n = m0 + nt * 16 + lo;  // m channel
    float bx = bias_x[w * 1024 + n];
    float bh = bias_h[w * 1024 + n];
#pragma unroll
    for (int r = 0; r < 4; ++r) {
      pre[w][quad * 4 + r][nt * 16 + lo] = acc[nt][r] + bx + bh;
    }
  }
  __syncthreads();

  // gate combine: 1024 elems / 256 threads = 4 each
#pragma unroll
  for (int j = 0; j < 4; ++j) {
    int e = threadIdx.x + 256 * j;
    int row = e >> 6, col = e & 63;
    int b = b0 + row, m = m0 + col;
    float fv = pre[0][row][col];
    float iv = pre[1][row][col];
    float nv = pre[2][row][col];
    float ov = pre[3][row][col];
    float cin = c[(size_t)b * 1024 + m];
    float ig = 1.f / (1.f + __expf(-iv));
    float fg = 1.f / (1.f + __expf(-fv));
    float og = 1.f / (1.f + __expf(-ov));
    float ng = tanhf(nv);
    float cn = fg * cin + ig * ng;
    float hn = og * tanhf(cn);
    out[(size_t)b * 1024 + m] = hn;
    out[(size_t)8192 * 1024 + (size_t)b * 1024 + m] = cn;
  }
}

extern "C" void kernel_launch(void* const* d_in, const int* in_sizes, int n_in,
                              void* d_out, int out_size, void* d_ws,
                              size_t ws_size, hipStream_t stream) {
  const float* x = (const float*)d_in[0];
  const float* h = (const float*)d_in[1];
  const float* c = (const float*)d_in[2];
  const float* u_x = (const float*)d_in[3];
  const float* v_x = (const float*)d_in[4];
  const float* u_h_0 = (const float*)d_in[5];
  const float* v_h_0 = (const float*)d_in[6];
  const float* u_h_1 = (const float*)d_in[7];
  const float* v_h_1 = (const float*)d_in[8];
  const float* bias_x = (const float*)d_in[9];
  const float* bias_h = (const float*)d_in[10];

  char* ws = (char*)d_ws;
  bf16_t* T = (bf16_t*)(ws + T_OFF);
  bf16_t* uxT = (bf16_t*)(ws + UXT_OFF);
  bf16_t* uhT = (bf16_t*)(ws + UHT_OFF);
  bf16_t* Wh = (bf16_t*)(ws + WH_OFF);

  prep_kernel<<<2816, 256, 0, stream>>>(u_x, u_h_0, u_h_1, v_h_0, v_h_1, uxT,
                                        uhT, Wh);
  phase1_kernel<<<512, 256, 0, stream>>>(x, h, uxT, uhT, T);
  phase2_kernel<<<dim3(512, 16), 256, 0, stream>>>(T, v_x, Wh, bias_x, bias_h,
                                                   c, (float*)d_out);
}

// Round 3
// 233.133 us; speedup vs baseline: 1.5406x; 1.5406x over previous
//
#include <hip/hip_runtime.h>
#include <hip/hip_bf16.h>

// Problem: B=8192, IN=1024, H=1024, G=2, hg=512, WR=64, UR=[64,64]
// All global tensors FLOAT32. MFMA on bf16; weights pre-packed to bf16 ws.
//
// ws layout (bytes):
//   T    @ 0        : 8192 x 320 bf16   = 5,242,880  (rank-space intermediate)
//   uxT  @ 5242880  : 64 x 1024 bf16    = 131,072    (u_x transposed)
//   uhT  @ 5373952  : 4 x 64 x 512 bf16 = 262,144    (u_h segments transposed)
//   Wb   @ 5636096  : 32 x 128 x 192    = 1,572,864  (unified gate weights,
//                      tile (g,qt): rows = w*32+ql -> [v_x | v_h] row, K=192)
// total 7,208,960 B

typedef __bf16 bf16_t;
typedef __bf16 bf16x8 __attribute__((ext_vector_type(8)));
typedef float f32x4 __attribute__((ext_vector_type(4)));

#define MFMA16x16x32(a, b, c) __builtin_amdgcn_mfma_f32_16x16x32_bf16((a), (b), (c), 0, 0, 0)

#define T_OFF 0
#define UXT_OFF 5242880
#define UHT_OFF 5373952
#define WB_OFF 5636096

// ---------------- prep: weight transposes + f32->bf16 + Wb pack ----------------
// uxT[j][k] = u_x[k][j]                                      (64 x 1024)
// uhT[s][j][d]: s0=(uh0,g0) s1=(uh1,g0) s2=(uh0,g1) s3=(uh1,g1)  (4 x 64 x 512)
// Wb[tile=g*16+qt][row=w*32+ql][k]:
//   m = g*512 + qt*32 + ql, q = qt*32+ql
//   k<64   : v_x[w*1024+m][k]
//   64..127: v_h_0[g][k-64][w*512+q]
//   128..  : v_h_1[g][k-128][w*512+q]
__global__ __launch_bounds__(256) void prep_kernel(
    const float* __restrict__ u_x, const float* __restrict__ u_h_0,
    const float* __restrict__ u_h_1, const float* __restrict__ v_h_0,
    const float* __restrict__ v_h_1, const float* __restrict__ v_x,
    bf16_t* __restrict__ uxT, bf16_t* __restrict__ uhT,
    bf16_t* __restrict__ Wb) {
  int i = blockIdx.x * 256 + threadIdx.x;
  if (i < 65536) {
    int j = i >> 10, k = i & 1023;
    uxT[i] = (bf16_t)u_x[k * 64 + j];
  } else if (i < 65536 + 131072) {
    int i2 = i - 65536;
    int s = i2 >> 15, rem = i2 & 32767;
    int j = rem >> 9, d = rem & 511;
    const float* src = (s & 1) ? u_h_1 : u_h_0;
    int goff = (s >> 1) ? 32768 : 0;  // g stride = 512*64
    uhT[i2] = (bf16_t)src[goff + d * 64 + j];
  } else if (i < 65536 + 131072 + 786432) {
    int e = i - 196608;
    int k = e % 192;
    int row = e / 192;          // 0..4095 global packed row
    int tile = row >> 7;        // g*16+qt
    int rr = row & 127;         // w*32+ql
    int g = tile >> 4, qt = tile & 15;
    int w = rr >> 5, ql = rr & 31;
    int m = g * 512 + qt * 32 + ql;
    int q = qt * 32 + ql;
    float val;
    if (k < 64)
      val = v_x[(w * 1024 + m) * 64 + k];
    else if (k < 128)
      val = v_h_0[g * 131072 + (k - 64) * 2048 + w * 512 + q];
    else
      val = v_h_1[g * 131072 + (k - 128) * 2048 + w * 512 + q];
    Wb[e] = (bf16_t)val;
  }
}

// ---------------- phase1: T = [x@u_x | h-slices @ u_h segs] ----------------
// Block = 16 b-rows. Stage x rows (bf16) in LDS -> 4 x-tiles (one per wave);
// restage with h -> 16 h-tiles (wave wv does s=wv, sub=0..3).
__global__ __launch_bounds__(256, 2) void phase1_kernel(
    const float* __restrict__ x, const float* __restrict__ h,
    const bf16_t* __restrict__ uxT, const bf16_t* __restrict__ uhT,
    bf16_t* __restrict__ T) {
  __shared__ bf16_t z[16][1048];  // pitch 1048: 2-way bank aliasing only
  const int b0 = blockIdx.x * 16;
  const int tid = threadIdx.x;
  const int wv = tid >> 6, lane = tid & 63;
  const int lo = lane & 15, quad = lane >> 4;
  const int srow = tid >> 4, sc = tid & 15;

  // ---- stage x: 16 rows x 1024 f32 -> bf16 LDS ----
  {
    const float* src = x + (size_t)(b0 + srow) * 1024;
#pragma unroll
    for (int j = 0; j < 16; ++j) {
      int col = sc * 4 + j * 64;
      float4 v = *(const float4*)(src + col);
      bf16_t* d = &z[srow][col];
      d[0] = (bf16_t)v.x; d[1] = (bf16_t)v.y;
      d[2] = (bf16_t)v.z; d[3] = (bf16_t)v.w;
    }
  }
  __syncthreads();

  // x tile: t = wv
  f32x4 accx = {0.f, 0.f, 0.f, 0.f};
  {
    const bf16_t* wBase = uxT + (size_t)(16 * wv + lo) * 1024;
    for (int k = 0; k < 1024; k += 32) {
      bf16x8 af = *(const bf16x8*)&z[lo][k + quad * 8];
      bf16x8 bfr = *(const bf16x8*)(wBase + k + quad * 8);
      accx = MFMA16x16x32(af, bfr, accx);
    }
  }
#pragma unroll
  for (int r = 0; r < 4; ++r)
    T[(size_t)(b0 + quad * 4 + r) * 320 + 16 * wv + lo] = (bf16_t)accx[r];
  __syncthreads();  // all reads of z done before restage

  // ---- stage h ----
  {
    const float* src = h + (size_t)(b0 + srow) * 1024;
#pragma unroll
    for (int j = 0; j < 16; ++j) {
      int col = sc * 4 + j * 64;
      float4 v = *(const float4*)(src + col);
      bf16_t* d = &z[srow][col];
      d[0] = (bf16_t)v.x; d[1] = (bf16_t)v.y;
      d[2] = (bf16_t)v.z; d[3] = (bf16_t)v.w;
    }
  }
  __syncthreads();

  // h tiles: s = wv (hoff: s0->0, s1->512, s2->512, s3->0), sub = 0..3
  const int hoff = (wv == 1 || wv == 2) ? 512 : 0;
#pragma unroll
  for (int sub = 0; sub < 4; ++sub) {
    const bf16_t* wBase = uhT + (size_t)(wv * 64 + 16 * sub + lo) * 512;
    f32x4 acc = {0.f, 0.f, 0.f, 0.f};
    for (int k = 0; k < 512; k += 32) {
      bf16x8 af = *(const bf16x8*)&z[lo][hoff + k + quad * 8];
      bf16x8 bfr = *(const bf16x8*)(wBase + k + quad * 8);
      acc = MFMA16x16x32(af, bfr, acc);
    }
    int n = 64 + wv * 64 + sub * 16 + lo;
#pragma unroll
    for (int r = 0; r < 4; ++r)
      T[(size_t)(b0 + quad * 4 + r) * 320 + n] = (bf16_t)acc[r];
  }
}

// ---------------- phase2: fused gate GEMM + cell update ----------------
// Block = 128 b-rows x 32 m-channels x 4 gates (N=128, K=192, no K-loop).
// Wave wv: 32 b-rows x full N. Lane holds all 4 gates per (b,m) -> fused
// epilogue with zero cross-lane traffic.
__global__ __launch_bounds__(256, 3) void phase2_kernel(
    const bf16_t* __restrict__ T, const bf16_t* __restrict__ Wb,
    const float* __restrict__ bias_x, const float* __restrict__ bias_h,
    const float* __restrict__ c, float* __restrict__ out) {
  __shared__ bf16_t bs[128][200];  // pitch 200: 2-way aliasing only

  const int b0 = blockIdx.x * 128;
  const int gq = blockIdx.y;  // g*16+qt
  const int g = gq >> 4, qt = gq & 15;
  const int tid = threadIdx.x;
  const int wv = tid >> 6, lane = tid & 63;
  const int lo = lane & 15, quad = lane >> 4;

  // stage B tile: contiguous 128x192 bf16 (48KB) -> padded LDS
  {
    const bf16_t* src = Wb + (size_t)gq * (128 * 192);
#pragma unroll
    for (int cch = 0; cch < 12; ++cch) {
      int lc = cch * 256 + tid;  // 0..3071 16B-chunks
      int row = lc / 24, col = (lc % 24) * 8;
      bf16x8 v = *(const bf16x8*)(src + (size_t)lc * 8);
      *(bf16x8*)&bs[row][col] = v;
    }
  }

  // A fragments direct from T (global, L2-hot): 12 bf16x8 per lane
  const int arow = b0 + wv * 32 + lo;
  bf16x8 a[2][6];
#pragma unroll
  for (int mt = 0; mt < 2; ++mt) {
    const bf16_t* tr = T + (size_t)(arow + mt * 16) * 320;
#pragma unroll
    for (int ks = 0; ks < 6; ++ks) {
      int col = (ks < 2) ? (ks * 32 + quad * 8)
                         : (64 + g * 128 + (ks - 2) * 32 + quad * 8);
      a[mt][ks] = *(const bf16x8*)(tr + col);
    }
  }
  __syncthreads();

  f32x4 acc[2][8];
#pragma unroll
  for (int mt = 0; mt < 2; ++mt)
#pragma unroll
    for (int nt = 0; nt < 8; ++nt) acc[mt][nt] = (f32x4){0.f, 0.f, 0.f, 0.f};

#pragma unroll
  for (int nt = 0; nt < 8; ++nt) {
#pragma unroll
    for (int ks = 0; ks < 6; ++ks) {
      bf16x8 bfr = *(const bf16x8*)&bs[nt * 16 + lo][ks * 32 + quad * 8];
      acc[0][nt] = MFMA16x16x32(a[0][ks], bfr, acc[0][nt]);
      acc[1][nt] = MFMA16x16x32(a[1][ks], bfr, acc[1][nt]);
    }
  }

  // biases: depend on (w, cq) only per lane
  float bsum[4][2];
#pragma unroll
  for (int w = 0; w < 4; ++w)
#pragma unroll
    for (int cq = 0; cq < 2; ++cq) {
      int m = g * 512 + qt * 32 + cq * 16 + lo;
      int n = w * 1024 + m;
      bsum[w][cq] = bias_x[n] + bias_h[n];
    }

  // fused epilogue: nt = w*2+cq -> all 4 gates in-lane
#pragma unroll
  for (int mt = 0; mt < 2; ++mt)
#pragma unroll
    for (int r = 0; r < 4; ++r) {
      int b = b0 + wv * 32 + mt * 16 + quad * 4 + r;
#pragma unroll
      for (int cq = 0; cq < 2; ++cq) {
        int m = g * 512 + qt * 32 + cq * 16 + lo;
        float fv = acc[mt][0 + cq][r] + bsum[0][cq];
        float iv = acc[mt][2 + cq][r] + bsum[1][cq];
        float nv = acc[mt][4 + cq][r] + bsum[2][cq];
        float ov = acc[mt][6 + cq][r] + bsum[3][cq];
        float cin = c[(size_t)b * 1024 + m];
        float ig = 1.f / (1.f + __expf(-iv));
        float fg = 1.f / (1.f + __expf(-fv));
        float og = 1.f / (1.f + __expf(-ov));
        float ng = tanhf(nv);
        float cn = fg * cin + ig * ng;
        float hn = og * tanhf(cn);
        out[(size_t)b * 1024 + m] = hn;
        out[8388608ull + (size_t)b * 1024 + m] = cn;
      }
    }
}

extern "C" void kernel_launch(void* const* d_in, const int* in_sizes, int n_in,
                              void* d_out, int out_size, void* d_ws,
                              size_t ws_size, hipStream_t stream) {
  const float* x = (const float*)d_in[0];
  const float* h = (const float*)d_in[1];
  const float* c = (const float*)d_in[2];
  const float* u_x = (const float*)d_in[3];
  const float* v_x = (const float*)d_in[4];
  const float* u_h_0 = (const float*)d_in[5];
  const float* v_h_0 = (const float*)d_in[6];
  const float* u_h_1 = (const float*)d_in[7];
  const float* v_h_1 = (const float*)d_in[8];
  const float* bias_x = (const float*)d_in[9];
  const float* bias_h = (const float*)d_in[10];

  char* ws = (char*)d_ws;
  bf16_t* T = (bf16_t*)(ws + T_OFF);
  bf16_t* uxT = (bf16_t*)(ws + UXT_OFF);
  bf16_t* uhT = (bf16_t*)(ws + UHT_OFF);
  bf16_t* Wb = (bf16_t*)(ws + WB_OFF);

  prep_kernel<<<3840, 256, 0, stream>>>(u_x, u_h_0, u_h_1, v_h_0, v_h_1, v_x,
                                        uxT, uhT, Wb);
  phase1_kernel<<<512, 256, 0, stream>>>(x, h, uxT, uhT, T);
  phase2_kernel<<<dim3(64, 32), 256, 0, stream>>>(T, Wb, bias_x, bias_h, c,
                                                  (float*)d_out);
}

// Round 4
// 210.042 us; speedup vs baseline: 1.7100x; 1.1099x over previous
//
#include <hip/hip_runtime.h>
#include <hip/hip_bf16.h>

// Problem: B=8192, IN=1024, H=1024, G=2, hg=512, WR=64, UR=[64,64]
// All global tensors FLOAT32. MFMA on bf16; weights pre-packed to bf16 ws.
//
// ws layout (bytes):
//   T    @ 0        : 8192 x 320 bf16   = 5,242,880  (rank-space intermediate)
//   uxT  @ 5242880  : 64 x 1024 bf16    = 131,072    (u_x transposed)
//   uhT  @ 5373952  : 4 x 64 x 512 bf16 = 262,144    (u_h segments transposed)
//   Wb   @ 5636096  : 32 x 128 x 192    = 1,572,864  (unified gate weights,
//                      tile (g,qt): rows = w*32+ql -> [v_x | v_h] row, K=192)
// total 7,208,960 B

typedef __bf16 bf16_t;
typedef __bf16 bf16x8 __attribute__((ext_vector_type(8)));
typedef float f32x4 __attribute__((ext_vector_type(4)));

#define MFMA16x16x32(a, b, c) __builtin_amdgcn_mfma_f32_16x16x32_bf16((a), (b), (c), 0, 0, 0)

#define T_OFF 0
#define UXT_OFF 5242880
#define UHT_OFF 5373952
#define WB_OFF 5636096

__device__ inline float fast_sigmoid(float x) {
  // rcp: ~1ulp, rcp(inf)=0 -> graceful saturation
  return __builtin_amdgcn_rcpf(1.f + __expf(-x));
}
__device__ inline float fast_tanh(float x) {
  return 2.f * __builtin_amdgcn_rcpf(1.f + __expf(-2.f * x)) - 1.f;
}

// ---------------- prep: coalesced-read repack (f32 -> bf16) ----------------
// uxT[j][k] = u_x[k][j]                                      (64 x 1024)
// uhT[s][j][d]: s = g*2 + uh_sel                             (4 x 64 x 512)
// Wb[tile=g*16+qt][row=w*32+ql][k]: k<64 v_x row | 64..127 v_h_0 | 128.. v_h_1
// All reads are consecutive-thread-consecutive-address; writes scatter (L2
// absorbs them, no latency stall).
__global__ __launch_bounds__(256) void prep_kernel(
    const float* __restrict__ u_x, const float* __restrict__ u_h_0,
    const float* __restrict__ u_h_1, const float* __restrict__ v_h_0,
    const float* __restrict__ v_h_1, const float* __restrict__ v_x,
    bf16_t* __restrict__ uxT, bf16_t* __restrict__ uhT,
    bf16_t* __restrict__ Wb) {
  int i = blockIdx.x * 256 + threadIdx.x;
  if (i < 65536) {
    // u_x[k][j], flat i = k*64 + j
    int k = i >> 6, j = i & 63;
    uxT[j * 1024 + k] = (bf16_t)u_x[i];
  } else if (i < 196608) {
    int i2 = i - 65536;            // 0..131071: [uh_sel][g][d][j]
    int uhs = i2 >> 16;
    int rem = i2 & 65535;          // g*32768 + d*64 + j
    int g = rem >> 15;
    int d = (rem >> 6) & 511, j = rem & 63;
    const float* src = uhs ? u_h_1 : u_h_0;
    int s = g * 2 + uhs;
    uhT[s * 32768 + j * 512 + d] = (bf16_t)src[rem];
  } else if (i < 458752) {
    // v_x (4096 x 64): flat a = (w*1024 + m)*64 + k
    int a = i - 196608;
    int row = a >> 6, k = a & 63;
    int w = row >> 10, m = row & 1023;
    int g = m >> 9, q = m & 511;
    int qt = q >> 5, ql = q & 31;
    Wb[(g * 16 + qt) * 24576 + (w * 32 + ql) * 192 + k] = (bf16_t)v_x[a];
  } else if (i < 720896) {
    // v_h_0 (2 x 64 x 2048): flat b2 = g*131072 + r*2048 + (w*512 + q)
    int b2 = i - 458752;
    int g = b2 >> 17, r = (b2 >> 11) & 63, col = b2 & 2047;
    int w = col >> 9, q = col & 511;
    int qt = q >> 5, ql = q & 31;
    Wb[(g * 16 + qt) * 24576 + (w * 32 + ql) * 192 + 64 + r] = (bf16_t)v_h_0[b2];
  } else if (i < 983040) {
    int c2 = i - 720896;
    int g = c2 >> 17, r = (c2 >> 11) & 63, col = c2 & 2047;
    int w = col >> 9, q = col & 511;
    int qt = q >> 5, ql = q & 31;
    Wb[(g * 16 + qt) * 24576 + (w * 32 + ql) * 192 + 128 + r] = (bf16_t)v_h_1[c2];
  }
}

// ---------------- phase1: T = [x@u_x | h-slices @ u_h segs] ----------------
// Block = 16 b-rows. Stage x rows (bf16) in LDS -> 4 x-tiles (one per wave);
// restage with h -> wave wv does s=wv, subs 0..3 with shared A ds_reads.
__global__ __launch_bounds__(256, 2) void phase1_kernel(
    const float* __restrict__ x, const float* __restrict__ h,
    const bf16_t* __restrict__ uxT, const bf16_t* __restrict__ uhT,
    bf16_t* __restrict__ T) {
  __shared__ bf16_t z[16][1048];  // pitch 1048 (2096B, 16B-aligned): 2-way only
  const int b0 = blockIdx.x * 16;
  const int tid = threadIdx.x;
  const int wv = tid >> 6, lane = tid & 63;
  const int lo = lane & 15, quad = lane >> 4;
  const int srow = tid >> 4, sc = tid & 15;

  // ---- stage x: 16 rows x 1024 f32 -> bf16 LDS ----
  {
    const float* src = x + (size_t)(b0 + srow) * 1024;
#pragma unroll
    for (int j = 0; j < 16; ++j) {
      int col = sc * 4 + j * 64;
      float4 v = *(const float4*)(src + col);
      bf16_t* d = &z[srow][col];
      d[0] = (bf16_t)v.x; d[1] = (bf16_t)v.y;
      d[2] = (bf16_t)v.z; d[3] = (bf16_t)v.w;
    }
  }
  __syncthreads();

  // x tile: t = wv
  f32x4 accx = {0.f, 0.f, 0.f, 0.f};
  {
    const bf16_t* wBase = uxT + (size_t)(16 * wv + lo) * 1024;
    for (int k = 0; k < 1024; k += 32) {
      bf16x8 af = *(const bf16x8*)&z[lo][k + quad * 8];
      bf16x8 bfr = *(const bf16x8*)(wBase + k + quad * 8);
      accx = MFMA16x16x32(af, bfr, accx);
    }
  }
#pragma unroll
  for (int r = 0; r < 4; ++r)
    T[(size_t)(b0 + quad * 4 + r) * 320 + 16 * wv + lo] = (bf16_t)accx[r];
  __syncthreads();  // all reads of z done before restage

  // ---- stage h ----
  {
    const float* src = h + (size_t)(b0 + srow) * 1024;
#pragma unroll
    for (int j = 0; j < 16; ++j) {
      int col = sc * 4 + j * 64;
      float4 v = *(const float4*)(src + col);
      bf16_t* d = &z[srow][col];
      d[0] = (bf16_t)v.x; d[1] = (bf16_t)v.y;
      d[2] = (bf16_t)v.z; d[3] = (bf16_t)v.w;
    }
  }
  __syncthreads();

  // h tiles: s = wv (hoff: s0->0, s1->512, s2->512, s3->0), 4 subs share each
  // A ds_read -> 4-way MFMA ILP per load.
  const int hoff = (wv == 1 || wv == 2) ? 512 : 0;
  f32x4 acc[4];
#pragma unroll
  for (int sub = 0; sub < 4; ++sub) acc[sub] = (f32x4){0.f, 0.f, 0.f, 0.f};
  {
    const bf16_t* wB = uhT + (size_t)(wv * 64 + lo) * 512;
    for (int k = 0; k < 512; k += 32) {
      bf16x8 af = *(const bf16x8*)&z[lo][hoff + k + quad * 8];
#pragma unroll
      for (int sub = 0; sub < 4; ++sub) {
        bf16x8 bfr = *(const bf16x8*)(wB + sub * (16 * 512) + k + quad * 8);
        acc[sub] = MFMA16x16x32(af, bfr, acc[sub]);
      }
    }
  }
#pragma unroll
  for (int sub = 0; sub < 4; ++sub) {
    int n = 64 + wv * 64 + sub * 16 + lo;
#pragma unroll
    for (int r = 0; r < 4; ++r)
      T[(size_t)(b0 + quad * 4 + r) * 320 + n] = (bf16_t)acc[sub][r];
  }
}

// ---------------- phase2: fused gate GEMM + cell update ----------------
// Block = 128 b-rows x 32 m-channels x 4 gates (N=128, K=192, no K-loop).
// Lane holds all 4 gates per (b,m) -> fused epilogue, zero cross-lane traffic.
__global__ __launch_bounds__(256, 3) void phase2_kernel(
    const bf16_t* __restrict__ T, const bf16_t* __restrict__ Wb,
    const float* __restrict__ bias_x, const float* __restrict__ bias_h,
    const float* __restrict__ c, float* __restrict__ out) {
  __shared__ bf16_t bs[128][200];  // pitch 200: 2-way aliasing only

  const int b0 = blockIdx.x * 128;
  const int gq = blockIdx.y;  // g*16+qt
  const int g = gq >> 4, qt = gq & 15;
  const int tid = threadIdx.x;
  const int wv = tid >> 6, lane = tid & 63;
  const int lo = lane & 15, quad = lane >> 4;

  // stage B tile: contiguous 128x192 bf16 (48KB) -> padded LDS
  {
    const bf16_t* src = Wb + (size_t)gq * (128 * 192);
#pragma unroll
    for (int cch = 0; cch < 12; ++cch) {
      int lc = cch * 256 + tid;  // 0..3071 16B-chunks
      int row = lc / 24, col = (lc % 24) * 8;
      bf16x8 v = *(const bf16x8*)(src + (size_t)lc * 8);
      *(bf16x8*)&bs[row][col] = v;
    }
  }

  // A fragments direct from T (global, L2-hot): 12 bf16x8 per lane
  const int arow = b0 + wv * 32 + lo;
  bf16x8 a[2][6];
#pragma unroll
  for (int mt = 0; mt < 2; ++mt) {
    const bf16_t* tr = T + (size_t)(arow + mt * 16) * 320;
#pragma unroll
    for (int ks = 0; ks < 6; ++ks) {
      int col = (ks < 2) ? (ks * 32 + quad * 8)
                         : (64 + g * 128 + (ks - 2) * 32 + quad * 8);
      a[mt][ks] = *(const bf16x8*)(tr + col);
    }
  }

  // prefetch c + biases (overlap with MFMA phase)
  float cin[2][4][2];
#pragma unroll
  for (int mt = 0; mt < 2; ++mt)
#pragma unroll
    for (int r = 0; r < 4; ++r) {
      int b = b0 + wv * 32 + mt * 16 + quad * 4 + r;
#pragma unroll
      for (int cq = 0; cq < 2; ++cq) {
        int m = g * 512 + qt * 32 + cq * 16 + lo;
        cin[mt][r][cq] = c[(size_t)b * 1024 + m];
      }
    }
  float bsum[4][2];
#pragma unroll
  for (int w = 0; w < 4; ++w)
#pragma unroll
    for (int cq = 0; cq < 2; ++cq) {
      int n = w * 1024 + g * 512 + qt * 32 + cq * 16 + lo;
      bsum[w][cq] = bias_x[n] + bias_h[n];
    }
  __syncthreads();

  f32x4 acc[2][8];
#pragma unroll
  for (int mt = 0; mt < 2; ++mt)
#pragma unroll
    for (int nt = 0; nt < 8; ++nt) acc[mt][nt] = (f32x4){0.f, 0.f, 0.f, 0.f};

#pragma unroll
  for (int nt = 0; nt < 8; ++nt) {
#pragma unroll
    for (int ks = 0; ks < 6; ++ks) {
      bf16x8 bfr = *(const bf16x8*)&bs[nt * 16 + lo][ks * 32 + quad * 8];
      acc[0][nt] = MFMA16x16x32(a[0][ks], bfr, acc[0][nt]);
      acc[1][nt] = MFMA16x16x32(a[1][ks], bfr, acc[1][nt]);
    }
  }

  // fused epilogue: nt = w*2+cq -> all 4 gates in-lane, fast transcendentals
#pragma unroll
  for (int mt = 0; mt < 2; ++mt)
#pragma unroll
    for (int r = 0; r < 4; ++r) {
      int b = b0 + wv * 32 + mt * 16 + quad * 4 + r;
#pragma unroll
      for (int cq = 0; cq < 2; ++cq) {
        int m = g * 512 + qt * 32 + cq * 16 + lo;
        float fv = acc[mt][0 + cq][r] + bsum[0][cq];
        float iv = acc[mt][2 + cq][r] + bsum[1][cq];
        float nv = acc[mt][4 + cq][r] + bsum[2][cq];
        float ov = acc[mt][6 + cq][r] + bsum[3][cq];
        float ig = fast_sigmoid(iv);
        float fg = fast_sigmoid(fv);
        float og = fast_sigmoid(ov);
        float ng = fast_tanh(nv);
        float cn = fg * cin[mt][r][cq] + ig * ng;
        float hn = og * fast_tanh(cn);
        out[(size_t)b * 1024 + m] = hn;
        out[8388608ull + (size_t)b * 1024 + m] = cn;
      }
    }
}

extern "C" void kernel_launch(void* const* d_in, const int* in_sizes, int n_in,
                              void* d_out, int out_size, void* d_ws,
                              size_t ws_size, hipStream_t stream) {
  const float* x = (const float*)d_in[0];
  const float* h = (const float*)d_in[1];
  const float* c = (const float*)d_in[2];
  const float* u_x = (const float*)d_in[3];
  const float* v_x = (const float*)d_in[4];
  const float* u_h_0 = (const float*)d_in[5];
  const float* v_h_0 = (const float*)d_in[6];
  const float* u_h_1 = (const float*)d_in[7];
  const float* v_h_1 = (const float*)d_in[8];
  const float* bias_x = (const float*)d_in[9];
  const float* bias_h = (const float*)d_in[10];

  char* ws = (char*)d_ws;
  bf16_t* T = (bf16_t*)(ws + T_OFF);
  bf16_t* uxT = (bf16_t*)(ws + UXT_OFF);
  bf16_t* uhT = (bf16_t*)(ws + UHT_OFF);
  bf16_t* Wb = (bf16_t*)(ws + WB_OFF);

  prep_kernel<<<3840, 256, 0, stream>>>(u_x, u_h_0, u_h_1, v_h_0, v_h_1, v_x,
                                        uxT, uhT, Wb);
  phase1_kernel<<<512, 256, 0, stream>>>(x, h, uxT, uhT, T);
  phase2_kernel<<<dim3(64, 32), 256, 0, stream>>>(T, Wb, bias_x, bias_h, c,
                                                  (float*)d_out);
}

// Round 5
// 205.895 us; speedup vs baseline: 1.7444x; 1.0201x over previous
//
#include <hip/hip_runtime.h>
#include <hip/hip_bf16.h>

// Problem: B=8192, IN=1024, H=1024, G=2, hg=512, WR=64, UR=[64,64]
// All global tensors FLOAT32. MFMA on bf16. All GEMM operands pre-swizzled
// into MFMA *fragment order* so every wave load is 64 lanes x 16 B contiguous.
//
// Fragment order convention (mfma_f32_16x16x32_bf16, verified layouts):
//   A-frag: lane(lo,quad) holds A[row=lo][k=quad*8+j], j=0..7
//   B-frag: lane(lo,quad) holds B[n=lo][k=quad*8+j]
//   D     : lane(lo,quad) holds D[row=quad*4+r][col=lo], r=0..3
//
// ws layout (bytes):
//   TA @ 0       : [rt:512][cc:10][lane:64][j:8] bf16 = 5,242,880
//                  (T in phase2-A-frag order; rt=b>>4, cc=col-chunk of 32)
//   Bx @ 5242880 : [t:4][kk:32][lane:64][8] bf16  = 131,072   (u_x frags)
//   Bh @ 5373952 : [s:4][sub:4][kk:16][lane:64][8] = 262,144  (u_h frags)
//   Bw @ 5636096 : [gq:32][nt:8][ks:6][lane:64][8] = 1,572,864 (gate-W frags)
// total 7,208,960 B

typedef __bf16 bf16_t;
typedef __bf16 bf16x4 __attribute__((ext_vector_type(4)));
typedef __bf16 bf16x8 __attribute__((ext_vector_type(8)));
typedef float f32x4 __attribute__((ext_vector_type(4)));

#define MFMA16x16x32(a, b, c) __builtin_amdgcn_mfma_f32_16x16x32_bf16((a), (b), (c), 0, 0, 0)

#define TA_OFF 0
#define BX_OFF 5242880
#define BH_OFF 5373952
#define BW_OFF 5636096

__device__ inline float fast_sigmoid(float x) {
  return __builtin_amdgcn_rcpf(1.f + __expf(-x));
}
__device__ inline float fast_tanh(float x) {
  return 2.f * __builtin_amdgcn_rcpf(1.f + __expf(-2.f * x)) - 1.f;
}

// ---------------- prep: output-indexed fragment packing ----------------
// Coalesced writes (consecutive tid -> consecutive output element); reads are
// small strided gathers into L2/L3-cached weight arrays (1.8 MB total).
__global__ __launch_bounds__(256) void prep_kernel(
    const float* __restrict__ u_x, const float* __restrict__ u_h_0,
    const float* __restrict__ u_h_1, const float* __restrict__ v_h_0,
    const float* __restrict__ v_h_1, const float* __restrict__ v_x,
    bf16_t* __restrict__ Bx, bf16_t* __restrict__ Bh,
    bf16_t* __restrict__ Bw) {
  int o = blockIdx.x * 256 + threadIdx.x;
  if (o < 65536) {
    // Bx[t][kk][lane][j] = u_x[k = kk*32+quad*8+j][n = 16t+lo]
    int j = o & 7, lane = (o >> 3) & 63, kk = (o >> 9) & 31, t = o >> 14;
    int lo = lane & 15, quad = lane >> 4;
    int k = kk * 32 + quad * 8 + j;
    Bx[o] = (bf16_t)u_x[k * 64 + 16 * t + lo];
  } else if (o < 196608) {
    // Bh[s][sub][kk][lane][j] = uh_{s&1}[g=s>>1][d = kk*32+quad*8+j][16sub+lo]
    int o2 = o - 65536;
    int j = o2 & 7, lane = (o2 >> 3) & 63, kk = (o2 >> 9) & 15;
    int sub = (o2 >> 13) & 3, s = o2 >> 15;
    int lo = lane & 15, quad = lane >> 4;
    int d = kk * 32 + quad * 8 + j;
    const float* src = (s & 1) ? u_h_1 : u_h_0;
    Bh[o2] = (bf16_t)src[(s >> 1) * 32768 + d * 64 + 16 * sub + lo];
  } else if (o < 983040) {
    // Bw[gq][nt][ks][lane][j]; row = 16nt+lo (= w*32+ql), k = ks*32+quad*8+j
    int o3 = o - 196608;
    int j = o3 & 7, lane = (o3 >> 3) & 63;
    int chunk = o3 >> 9;          // (gq*8+nt)*6 + ks
    int ks = chunk % 6, rowt = chunk / 6;
    int gq = rowt >> 3, nt = rowt & 7;
    int lo = lane & 15, quad = lane >> 4;
    int g = gq >> 4, qt = gq & 15;
    int row = 16 * nt + lo;
    int w = row >> 5, ql = row & 31;
    int k = ks * 32 + quad * 8 + j;
    int m = g * 512 + qt * 32 + ql;
    int q = qt * 32 + ql;
    float val;
    if (k < 64)
      val = v_x[(w * 1024 + m) * 64 + k];
    else if (k < 128)
      val = v_h_0[g * 131072 + (k - 64) * 2048 + w * 512 + q];
    else
      val = v_h_1[g * 131072 + (k - 128) * 2048 + w * 512 + q];
    Bw[o3] = (bf16_t)val;
  }
}

// ---------------- phase1: TA = frag-ordered [x@u_x | h @ u_h segs] ----------
// Block = 16 b-rows. A (x then h) staged in LDS as bf16; B-frags are single
// coalesced global loads; results transposed D->A-frag layout via LDS 'pre'
// and written out as coalesced 16B stores.
__global__ __launch_bounds__(256) void phase1_kernel(
    const float* __restrict__ x, const float* __restrict__ h,
    const bf16_t* __restrict__ Bx, const bf16_t* __restrict__ Bh,
    bf16_t* __restrict__ TA) {
  __shared__ bf16_t z[16][1048];   // pitch 1048: 2-way aliasing only
  __shared__ bf16_t pre[16][328];  // T-tile (16 x 320), pitch 328
  const int b0 = blockIdx.x * 16;
  const int tid = threadIdx.x;
  const int wv = tid >> 6, lane = tid & 63;
  const int lo = lane & 15, quad = lane >> 4;
  const int srow = tid >> 4, sc = tid & 15;

  // ---- stage x: 16 rows x 1024 f32 -> bf16 LDS (packed b64 writes) ----
  {
    const float* src = x + (size_t)(b0 + srow) * 1024;
#pragma unroll
    for (int j = 0; j < 16; ++j) {
      int col = sc * 4 + j * 64;
      float4 v = *(const float4*)(src + col);
      bf16x4 pk;
      pk[0] = (bf16_t)v.x; pk[1] = (bf16_t)v.y;
      pk[2] = (bf16_t)v.z; pk[3] = (bf16_t)v.w;
      *(bf16x4*)&z[srow][col] = pk;
    }
  }
  __syncthreads();

  // x tile: t = wv (T cols 16wv..16wv+15)
  {
    f32x4 accx = {0.f, 0.f, 0.f, 0.f};
    const bf16_t* bx = Bx + ((size_t)(wv * 32) * 64 + lane) * 8;
    for (int kk = 0; kk < 32; ++kk) {
      bf16x8 af = *(const bf16x8*)&z[lo][kk * 32 + quad * 8];
      bf16x8 bfr = *(const bf16x8*)(bx + (size_t)kk * 512);
      accx = MFMA16x16x32(af, bfr, accx);
    }
#pragma unroll
    for (int r = 0; r < 4; ++r) pre[quad * 4 + r][16 * wv + lo] = (bf16_t)accx[r];
  }
  __syncthreads();  // z reads done before restage

  // ---- stage h ----
  {
    const float* src = h + (size_t)(b0 + srow) * 1024;
#pragma unroll
    for (int j = 0; j < 16; ++j) {
      int col = sc * 4 + j * 64;
      float4 v = *(const float4*)(src + col);
      bf16x4 pk;
      pk[0] = (bf16_t)v.x; pk[1] = (bf16_t)v.y;
      pk[2] = (bf16_t)v.z; pk[3] = (bf16_t)v.w;
      *(bf16x4*)&z[srow][col] = pk;
    }
  }
  __syncthreads();

  // h tiles: s = wv (hoff: s0->0, s1->512, s2->512, s3->0); one A ds_read
  // feeds 4 coalesced B-frag loads + 4 MFMAs.
  {
    const int hoff = (wv == 1 || wv == 2) ? 512 : 0;
    f32x4 acc[4];
#pragma unroll
    for (int sub = 0; sub < 4; ++sub) acc[sub] = (f32x4){0.f, 0.f, 0.f, 0.f};
    for (int kk = 0; kk < 16; ++kk) {
      bf16x8 af = *(const bf16x8*)&z[lo][hoff + kk * 32 + quad * 8];
#pragma unroll
      for (int sub = 0; sub < 4; ++sub) {
        bf16x8 bfr = *(const bf16x8*)(Bh +
            (((size_t)(wv * 4 + sub) * 16 + kk) * 64 + lane) * 8);
        acc[sub] = MFMA16x16x32(af, bfr, acc[sub]);
      }
    }
#pragma unroll
    for (int sub = 0; sub < 4; ++sub) {
      int n = 64 + wv * 64 + sub * 16 + lo;
#pragma unroll
      for (int r = 0; r < 4; ++r) pre[quad * 4 + r][n] = (bf16_t)acc[sub][r];
    }
  }
  __syncthreads();

  // write out TA in A-frag order: 10 cc-chunks x 64 lanes, coalesced 16B
#pragma unroll
  for (int it = 0; it < 3; ++it) {
    int slot = it * 256 + tid;
    if (slot < 640) {
      int cc = slot >> 6, ln = slot & 63;
      int llo = ln & 15, lq = ln >> 4;
      bf16x8 v = *(const bf16x8*)&pre[llo][cc * 32 + lq * 8];
      *(bf16x8*)(TA + (((size_t)blockIdx.x * 10 + cc) * 64 + ln) * 8) = v;
    }
  }
}

// ---------------- phase2: fused gate GEMM + cell update (no LDS) ----------
// Block = 128 b-rows x 32 m-channels x 4 gates. Wave = 32 rows. All operand
// loads coalesced fragment loads; no barrier; lane holds all 4 gates per
// (b,m) -> pure in-lane epilogue.
__global__ __launch_bounds__(256, 3) void phase2_kernel(
    const bf16_t* __restrict__ TA, const bf16_t* __restrict__ Bw,
    const float* __restrict__ bias_x, const float* __restrict__ bias_h,
    const float* __restrict__ c, float* __restrict__ out) {
  const int b0 = blockIdx.x * 128;
  const int gq = blockIdx.y;  // g*16+qt
  const int g = gq >> 4, qt = gq & 15;
  const int tid = threadIdx.x;
  const int wv = tid >> 6, lane = tid & 63;
  const int lo = lane & 15, quad = lane >> 4;

  // A-frags: 12 coalesced loads from TA
  bf16x8 a[2][6];
#pragma unroll
  for (int mt = 0; mt < 2; ++mt) {
    int rt = blockIdx.x * 8 + wv * 2 + mt;
#pragma unroll
    for (int ks = 0; ks < 6; ++ks) {
      int cc = (ks < 2) ? ks : (g * 4 + ks);
      a[mt][ks] = *(const bf16x8*)(TA + (((size_t)rt * 10 + cc) * 64 + lane) * 8);
    }
  }

  float bsum[4][2];
#pragma unroll
  for (int w = 0; w < 4; ++w)
#pragma unroll
    for (int cq = 0; cq < 2; ++cq) {
      int n = w * 1024 + g * 512 + qt * 32 + cq * 16 + lo;
      bsum[w][cq] = bias_x[n] + bias_h[n];
    }

  f32x4 acc[2][8];
#pragma unroll
  for (int mt = 0; mt < 2; ++mt)
#pragma unroll
    for (int nt = 0; nt < 8; ++nt) acc[mt][nt] = (f32x4){0.f, 0.f, 0.f, 0.f};

#pragma unroll
  for (int nt = 0; nt < 8; ++nt) {
#pragma unroll
    for (int ks = 0; ks < 6; ++ks) {
      bf16x8 bfr = *(const bf16x8*)(Bw +
          (((size_t)(gq * 8 + nt) * 6 + ks) * 64 + lane) * 8);
      acc[0][nt] = MFMA16x16x32(a[0][ks], bfr, acc[0][nt]);
      acc[1][nt] = MFMA16x16x32(a[1][ks], bfr, acc[1][nt]);
    }
  }

  // fused epilogue: nt = w*2+cq -> all 4 gates in-lane
#pragma unroll
  for (int mt = 0; mt < 2; ++mt)
#pragma unroll
    for (int r = 0; r < 4; ++r) {
      int b = b0 + wv * 32 + mt * 16 + quad * 4 + r;
#pragma unroll
      for (int cq = 0; cq < 2; ++cq) {
        int m = g * 512 + qt * 32 + cq * 16 + lo;
        float fv = acc[mt][0 + cq][r] + bsum[0][cq];
        float iv = acc[mt][2 + cq][r] + bsum[1][cq];
        float nv = acc[mt][4 + cq][r] + bsum[2][cq];
        float ov = acc[mt][6 + cq][r] + bsum[3][cq];
        float cin = c[(size_t)b * 1024 + m];
        float ig = fast_sigmoid(iv);
        float fg = fast_sigmoid(fv);
        float og = fast_sigmoid(ov);
        float ng = fast_tanh(nv);
        float cn = fg * cin + ig * ng;
        float hn = og * fast_tanh(cn);
        out[(size_t)b * 1024 + m] = hn;
        out[8388608ull + (size_t)b * 1024 + m] = cn;
      }
    }
}

extern "C" void kernel_launch(void* const* d_in, const int* in_sizes, int n_in,
                              void* d_out, int out_size, void* d_ws,
                              size_t ws_size, hipStream_t stream) {
  const float* x = (const float*)d_in[0];
  const float* h = (const float*)d_in[1];
  const float* c = (const float*)d_in[2];
  const float* u_x = (const float*)d_in[3];
  const float* v_x = (const float*)d_in[4];
  const float* u_h_0 = (const float*)d_in[5];
  const float* v_h_0 = (const float*)d_in[6];
  const float* u_h_1 = (const float*)d_in[7];
  const float* v_h_1 = (const float*)d_in[8];
  const float* bias_x = (const float*)d_in[9];
  const float* bias_h = (const float*)d_in[10];

  char* ws = (char*)d_ws;
  bf16_t* TA = (bf16_t*)(ws + TA_OFF);
  bf16_t* Bx = (bf16_t*)(ws + BX_OFF);
  bf16_t* Bh = (bf16_t*)(ws + BH_OFF);
  bf16_t* Bw = (bf16_t*)(ws + BW_OFF);

  prep_kernel<<<3840, 256, 0, stream>>>(u_x, u_h_0, u_h_1, v_h_0, v_h_1, v_x,
                                        Bx, Bh, Bw);
  phase1_kernel<<<512, 256, 0, stream>>>(x, h, Bx, Bh, TA);
  phase2_kernel<<<dim3(64, 32), 256, 0, stream>>>(TA, Bw, bias_x, bias_h, c,
                                                  (float*)d_out);
}

// Round 6
// 191.466 us; speedup vs baseline: 1.8759x; 1.0754x over previous
//
#include <hip/hip_runtime.h>
#include <hip/hip_bf16.h>

// Problem: B=8192, IN=1024, H=1024, G=2, hg=512, WR=64, UR=[64,64]
// All global tensors FLOAT32. MFMA on bf16. All GEMM operands pre-swizzled
// into MFMA fragment order so every wave load is 64 lanes x 16 B contiguous.
//
// Fragment order (mfma_f32_16x16x32_bf16, verified layouts):
//   A-frag: lane(lo,quad) holds A[row=lo][k=quad*8+j], j=0..7
//   B-frag: lane(lo,quad) holds B[n=lo][k=quad*8+j]
//   D     : lane(lo,quad) holds D[row=quad*4+r][col=lo], r=0..3
//
// ws layout (bytes):
//   TA @ 0       : [rt:512][cc:10][lane:64][j:8] bf16 = 5,242,880
//   Bx @ 5242880 : [t:4][kk:32][lane:64][8] bf16  = 131,072   (u_x frags)
//   Bh @ 5373952 : [s:4][sub:4][kk:16][lane:64][8] = 262,144  (u_h frags)
//   Bw @ 5636096 : [gq:32][nt:8][ks:6][lane:64][8] = 1,572,864 (gate-W frags)
// total 7,208,960 B

typedef __bf16 bf16_t;
typedef __bf16 bf16x4 __attribute__((ext_vector_type(4)));
typedef __bf16 bf16x8 __attribute__((ext_vector_type(8)));
typedef float f32x4 __attribute__((ext_vector_type(4)));

#define MFMA16x16x32(a, b, c) __builtin_amdgcn_mfma_f32_16x16x32_bf16((a), (b), (c), 0, 0, 0)

#define TA_OFF 0
#define BX_OFF 5242880
#define BH_OFF 5373952
#define BW_OFF 5636096

__device__ inline float fast_sigmoid(float x) {
  return __builtin_amdgcn_rcpf(1.f + __expf(-x));
}
__device__ inline float fast_tanh(float x) {
  return 2.f * __builtin_amdgcn_rcpf(1.f + __expf(-2.f * x)) - 1.f;
}

// ---------------- prep: output-indexed fragment packing ----------------
__global__ __launch_bounds__(256) void prep_kernel(
    const float* __restrict__ u_x, const float* __restrict__ u_h_0,
    const float* __restrict__ u_h_1, const float* __restrict__ v_h_0,
    const float* __restrict__ v_h_1, const float* __restrict__ v_x,
    bf16_t* __restrict__ Bx, bf16_t* __restrict__ Bh,
    bf16_t* __restrict__ Bw) {
  int o = blockIdx.x * 256 + threadIdx.x;
  if (o < 65536) {
    // Bx[t][kk][lane][j] = u_x[k = kk*32+quad*8+j][n = 16t+lo]
    int j = o & 7, lane = (o >> 3) & 63, kk = (o >> 9) & 31, t = o >> 14;
    int lo = lane & 15, quad = lane >> 4;
    int k = kk * 32 + quad * 8 + j;
    Bx[o] = (bf16_t)u_x[k * 64 + 16 * t + lo];
  } else if (o < 196608) {
    // Bh[s][sub][kk][lane][j] = uh_{s&1}[g=s>>1][d = kk*32+quad*8+j][16sub+lo]
    int o2 = o - 65536;
    int j = o2 & 7, lane = (o2 >> 3) & 63, kk = (o2 >> 9) & 15;
    int sub = (o2 >> 13) & 3, s = o2 >> 15;
    int lo = lane & 15, quad = lane >> 4;
    int d = kk * 32 + quad * 8 + j;
    const float* src = (s & 1) ? u_h_1 : u_h_0;
    Bh[o2] = (bf16_t)src[(s >> 1) * 32768 + d * 64 + 16 * sub + lo];
  } else if (o < 983040) {
    // Bw[gq][nt][ks][lane][j]; row = 16nt+lo (= w*32+ql), k = ks*32+quad*8+j
    int o3 = o - 196608;
    int j = o3 & 7, lane = (o3 >> 3) & 63;
    int chunk = o3 >> 9;          // (gq*8+nt)*6 + ks
    int ks = chunk % 6, rowt = chunk / 6;
    int gq = rowt >> 3, nt = rowt & 7;
    int lo = lane & 15, quad = lane >> 4;
    int g = gq >> 4, qt = gq & 15;
    int row = 16 * nt + lo;
    int w = row >> 5, ql = row & 31;
    int k = ks * 32 + quad * 8 + j;
    int m = g * 512 + qt * 32 + ql;
    int q = qt * 32 + ql;
    float val;
    if (k < 64)
      val = v_x[(w * 1024 + m) * 64 + k];
    else if (k < 128)
      val = v_h_0[g * 131072 + (k - 64) * 2048 + w * 512 + q];
    else
      val = v_h_1[g * 131072 + (k - 128) * 2048 + w * 512 + q];
    Bw[o3] = (bf16_t)val;
  }
}

// ---------------- phase1: TA = frag-ordered [x@u_x | h @ u_h segs] ----------
// Block = 16 b-rows. Single-stage: x AND h staged together (one barrier, both
// staging load streams in flight simultaneously). B-frags are coalesced
// global loads; D->A-frag transpose via 'pre'; coalesced 16B TA stores.
__global__ __launch_bounds__(256) void phase1_kernel(
    const float* __restrict__ x, const float* __restrict__ h,
    const bf16_t* __restrict__ Bx, const bf16_t* __restrict__ Bh,
    bf16_t* __restrict__ TA) {
  __shared__ bf16_t z[16][2072];   // cols 0..1023 = x, 1024..2047 = h
  __shared__ bf16_t pre[16][328];  // T-tile (16 x 320)
  const int b0 = blockIdx.x * 16;
  const int tid = threadIdx.x;
  const int wv = tid >> 6, lane = tid & 63;
  const int lo = lane & 15, quad = lane >> 4;
  const int srow = tid >> 4, sc = tid & 15;

  // ---- stage x+h: 16 rows x (1024+1024) f32 -> bf16 LDS ----
  {
    const float* srcx = x + (size_t)(b0 + srow) * 1024;
    const float* srch = h + (size_t)(b0 + srow) * 1024;
#pragma unroll
    for (int j = 0; j < 16; ++j) {
      int col = sc * 4 + j * 64;
      float4 v = *(const float4*)(srcx + col);
      bf16x4 pk;
      pk[0] = (bf16_t)v.x; pk[1] = (bf16_t)v.y;
      pk[2] = (bf16_t)v.z; pk[3] = (bf16_t)v.w;
      *(bf16x4*)&z[srow][col] = pk;
    }
#pragma unroll
    for (int j = 0; j < 16; ++j) {
      int col = sc * 4 + j * 64;
      float4 v = *(const float4*)(srch + col);
      bf16x4 pk;
      pk[0] = (bf16_t)v.x; pk[1] = (bf16_t)v.y;
      pk[2] = (bf16_t)v.z; pk[3] = (bf16_t)v.w;
      *(bf16x4*)&z[srow][1024 + col] = pk;
    }
  }
  __syncthreads();

  // x tile: t = wv (T cols 16wv..16wv+15)
  {
    f32x4 accx = {0.f, 0.f, 0.f, 0.f};
    const bf16_t* bx = Bx + ((size_t)(wv * 32) * 64 + lane) * 8;
    for (int kk = 0; kk < 32; ++kk) {
      bf16x8 af = *(const bf16x8*)&z[lo][kk * 32 + quad * 8];
      bf16x8 bfr = *(const bf16x8*)(bx + (size_t)kk * 512);
      accx = MFMA16x16x32(af, bfr, accx);
    }
#pragma unroll
    for (int r = 0; r < 4; ++r) pre[quad * 4 + r][16 * wv + lo] = (bf16_t)accx[r];
  }

  // h tiles: s = wv (hoff: s0->0, s1->512, s2->512, s3->0); one A ds_read
  // feeds 4 coalesced B-frag loads + 4 MFMAs. No barrier needed: z is
  // read-only now, pre columns are per-wave disjoint.
  {
    const int hoff = 1024 + ((wv == 1 || wv == 2) ? 512 : 0);
    f32x4 acc[4];
#pragma unroll
    for (int sub = 0; sub < 4; ++sub) acc[sub] = (f32x4){0.f, 0.f, 0.f, 0.f};
    for (int kk = 0; kk < 16; ++kk) {
      bf16x8 af = *(const bf16x8*)&z[lo][hoff + kk * 32 + quad * 8];
#pragma unroll
      for (int sub = 0; sub < 4; ++sub) {
        bf16x8 bfr = *(const bf16x8*)(Bh +
            (((size_t)(wv * 4 + sub) * 16 + kk) * 64 + lane) * 8);
        acc[sub] = MFMA16x16x32(af, bfr, acc[sub]);
      }
    }
#pragma unroll
    for (int sub = 0; sub < 4; ++sub) {
      int n = 64 + wv * 64 + sub * 16 + lo;
#pragma unroll
      for (int r = 0; r < 4; ++r) pre[quad * 4 + r][n] = (bf16_t)acc[sub][r];
    }
  }
  __syncthreads();

  // write out TA in A-frag order: 10 cc-chunks x 64 lanes, coalesced 16B
#pragma unroll
  for (int it = 0; it < 3; ++it) {
    int slot = it * 256 + tid;
    if (slot < 640) {
      int cc = slot >> 6, ln = slot & 63;
      int llo = ln & 15, lq = ln >> 4;
      bf16x8 v = *(const bf16x8*)&pre[llo][cc * 32 + lq * 8];
      *(bf16x8*)(TA + (((size_t)blockIdx.x * 10 + cc) * 64 + ln) * 8) = v;
    }
  }
}

// ---------------- phase2: fused gate GEMM + cell update ----------------
// Block = 128 b-rows x 32 m-channels x 4 gates. B tile staged in LDS in
// frag-linear order (conflict-free b128 both directions); A-frags coalesced
// from TA into registers; c/bias prefetched; single barrier. Lane holds all
// 4 gates per (b,m) -> pure in-lane epilogue.
__global__ __launch_bounds__(256, 3) void phase2_kernel(
    const bf16_t* __restrict__ TA, const bf16_t* __restrict__ Bw,
    const float* __restrict__ bias_x, const float* __restrict__ bias_h,
    const float* __restrict__ c, float* __restrict__ out) {
  __shared__ bf16_t bs[3072 * 8];  // 48KB, frag-linear [nt][ks][lane][8]

  const int b0 = blockIdx.x * 128;
  const int gq = blockIdx.y;  // g*16+qt
  const int g = gq >> 4, qt = gq & 15;
  const int tid = threadIdx.x;
  const int wv = tid >> 6, lane = tid & 63;
  const int lo = lane & 15, quad = lane >> 4;

  // A-frags: 12 coalesced loads from TA (issue early, drained at barrier)
  bf16x8 a[2][6];
#pragma unroll
  for (int mt = 0; mt < 2; ++mt) {
    int rt = blockIdx.x * 8 + wv * 2 + mt;
#pragma unroll
    for (int ks = 0; ks < 6; ++ks) {
      int cc = (ks < 2) ? ks : (g * 4 + ks);
      a[mt][ks] = *(const bf16x8*)(TA + (((size_t)rt * 10 + cc) * 64 + lane) * 8);
    }
  }

  // stage B tile: 3072 16B-chunks, global and LDS both frag-linear
  {
    const bf16_t* src = Bw + (size_t)gq * 24576;
#pragma unroll
    for (int cch = 0; cch < 12; ++cch) {
      int ch = cch * 256 + tid;
      *(bf16x8*)&bs[(size_t)ch * 8] = *(const bf16x8*)(src + (size_t)ch * 8);
    }
  }

  // prefetch c + biases (overlap with load drain)
  float cin[2][4][2];
#pragma unroll
  for (int mt = 0; mt < 2; ++mt)
#pragma unroll
    for (int r = 0; r < 4; ++r) {
      int b = b0 + wv * 32 + mt * 16 + quad * 4 + r;
#pragma unroll
      for (int cq = 0; cq < 2; ++cq) {
        int m = g * 512 + qt * 32 + cq * 16 + lo;
        cin[mt][r][cq] = c[(size_t)b * 1024 + m];
      }
    }
  float bsum[4][2];
#pragma unroll
  for (int w = 0; w < 4; ++w)
#pragma unroll
    for (int cq = 0; cq < 2; ++cq) {
      int n = w * 1024 + g * 512 + qt * 32 + cq * 16 + lo;
      bsum[w][cq] = bias_x[n] + bias_h[n];
    }
  __syncthreads();

  f32x4 acc[2][8];
#pragma unroll
  for (int mt = 0; mt < 2; ++mt)
#pragma unroll
    for (int nt = 0; nt < 8; ++nt) acc[mt][nt] = (f32x4){0.f, 0.f, 0.f, 0.f};

#pragma unroll
  for (int nt = 0; nt < 8; ++nt) {
#pragma unroll
    for (int ks = 0; ks < 6; ++ks) {
      bf16x8 bfr = *(const bf16x8*)&bs[(size_t)(((nt * 6 + ks) << 6) + lane) * 8];
      acc[0][nt] = MFMA16x16x32(a[0][ks], bfr, acc[0][nt]);
      acc[1][nt] = MFMA16x16x32(a[1][ks], bfr, acc[1][nt]);
    }
  }

  // fused epilogue: nt = w*2+cq -> all 4 gates in-lane
#pragma unroll
  for (int mt = 0; mt < 2; ++mt)
#pragma unroll
    for (int r = 0; r < 4; ++r) {
      int b = b0 + wv * 32 + mt * 16 + quad * 4 + r;
#pragma unroll
      for (int cq = 0; cq < 2; ++cq) {
        int m = g * 512 + qt * 32 + cq * 16 + lo;
        float fv = acc[mt][0 + cq][r] + bsum[0][cq];
        float iv = acc[mt][2 + cq][r] + bsum[1][cq];
        float nv = acc[mt][4 + cq][r] + bsum[2][cq];
        float ov = acc[mt][6 + cq][r] + bsum[3][cq];
        float ig = fast_sigmoid(iv);
        float fg = fast_sigmoid(fv);
        float og = fast_sigmoid(ov);
        float ng = fast_tanh(nv);
        float cn = fg * cin[mt][r][cq] + ig * ng;
        float hn = og * fast_tanh(cn);
        out[(size_t)b * 1024 + m] = hn;
        out[8388608ull + (size_t)b * 1024 + m] = cn;
      }
    }
}

extern "C" void kernel_launch(void* const* d_in, const int* in_sizes, int n_in,
                              void* d_out, int out_size, void* d_ws,
                              size_t ws_size, hipStream_t stream) {
  const float* x = (const float*)d_in[0];
  const float* h = (const float*)d_in[1];
  const float* c = (const float*)d_in[2];
  const float* u_x = (const float*)d_in[3];
  const float* v_x = (const float*)d_in[4];
  const float* u_h_0 = (const float*)d_in[5];
  const float* v_h_0 = (const float*)d_in[6];
  const float* u_h_1 = (const float*)d_in[7];
  const float* v_h_1 = (const float*)d_in[8];
  const float* bias_x = (const float*)d_in[9];
  const float* bias_h = (const float*)d_in[10];

  char* ws = (char*)d_ws;
  bf16_t* TA = (bf16_t*)(ws + TA_OFF);
  bf16_t* Bx = (bf16_t*)(ws + BX_OFF);
  bf16_t* Bh = (bf16_t*)(ws + BH_OFF);
  bf16_t* Bw = (bf16_t*)(ws + BW_OFF);

  prep_kernel<<<3840, 256, 0, stream>>>(u_x, u_h_0, u_h_1, v_h_0, v_h_1, v_x,
                                        Bx, Bh, Bw);
  phase1_kernel<<<512, 256, 0, stream>>>(x, h, Bx, Bh, TA);
  phase2_kernel<<<dim3(64, 32), 256, 0, stream>>>(TA, Bw, bias_x, bias_h, c,
                                                  (float*)d_out);
}